// Round 22
// baseline (189.441 us; speedup 1.0000x reference)
//
#include <hip/hip_runtime.h>
#include <hip/hip_bf16.h>
#include <hip/hip_fp16.h>

// GCN 2-layer forward, CSR-gather formulation.
// R22 = R21 (best, 181us) + ONE change: k_csr scatters csr_src directly to
// global (stage[CAP2] LDS array deleted). The 37KB stage forced 1-2 blocks/CU;
// the bucket's csr segment (~32KB) is written within one block's lifetime so
// L2 merges the scatter lines without staging (R8's temporal-merge lesson).
// LDS 40KB -> 3KB, one m-element LDS pass + sync removed.

#define NB2 256        // nodes per bucket (power of 2: shift/mask)
#define CAP2 9472      // per-bucket edge capacity (mean 8184, +14 sigma)
#define MAXB 400       // static LDS sizing bound for bucket count
#define BIN_CHUNK 8192

__global__ __launch_bounds__(512) void k_bin(const int* __restrict__ src,
                                             const int* __restrict__ dst,
                                             int E, int nbuckets,
                                             int* __restrict__ binCnt,
                                             int* __restrict__ bins) {
    __shared__ int stageP[BIN_CHUNK];            // packed src|dloc (32 KB)
    __shared__ unsigned short stageB[BIN_CHUNK]; // bucket id (16 KB)
    __shared__ int lcnt[MAXB];
    __shared__ int lbase[MAXB + 1];
    __shared__ int gbase[MAXB];
    __shared__ int lpos[MAXB];
    int base = blockIdx.x * BIN_CHUNK;
    if (base >= E) return;
    int cnt_here = min(BIN_CHUNK, E - base);

    for (int b = threadIdx.x; b < nbuckets; b += 512) lcnt[b] = 0;
    __syncthreads();

    int p_[16], b_[16];
    #pragma unroll
    for (int k = 0; k < 4; k++) {
        int e0 = base + (k * 512 + threadIdx.x) * 4;
        int s4[4], d4[4];
        if (e0 + 3 < E) {
            *reinterpret_cast<int4*>(s4) = *reinterpret_cast<const int4*>(src + e0);
            *reinterpret_cast<int4*>(d4) = *reinterpret_cast<const int4*>(dst + e0);
            #pragma unroll
            for (int j = 0; j < 4; j++) {
                int b = d4[j] >> 8;
                b_[4 * k + j] = b;
                p_[4 * k + j] = s4[j] | ((d4[j] & 255) << 17);
                atomicAdd(&lcnt[b], 1);
            }
        } else {
            #pragma unroll
            for (int j = 0; j < 4; j++) {
                int e = e0 + j;
                if (e < E) {
                    int s = src[e], d = dst[e];
                    int b = d >> 8;
                    b_[4 * k + j] = b;
                    p_[4 * k + j] = s | ((d & 255) << 17);
                    atomicAdd(&lcnt[b], 1);
                } else {
                    b_[4 * k + j] = -1;
                }
            }
        }
    }
    __syncthreads();

    // Wave-parallel exclusive scan of lcnt (first wave only).
    if (threadIdx.x < 64) {
        int lane = threadIdx.x;
        int per = (nbuckets + 63) >> 6;   // ≤ 7
        int start = lane * per;
        int v[8];
        int s = 0;
        for (int i = 0; i < per; ++i) {
            int b = start + i;
            v[i] = (b < nbuckets) ? lcnt[b] : 0;
            s += v[i];
        }
        int run = s;
        #pragma unroll
        for (int off = 1; off < 64; off <<= 1) {
            int t = __shfl_up(run, off);
            if (lane >= off) run += t;
        }
        int acc = run - s;
        for (int i = 0; i < per; ++i) {
            int b = start + i;
            if (b < nbuckets) lbase[b] = acc;
            acc += v[i];
        }
        if (lane == 63) lbase[nbuckets] = run;
    }
    __syncthreads();
    for (int b = threadIdx.x; b < nbuckets; b += 512) {
        gbase[b] = atomicAdd(&binCnt[b], lcnt[b]);
        lpos[b] = lbase[b];
    }
    __syncthreads();
    #pragma unroll
    for (int k = 0; k < 16; k++) {
        if (b_[k] >= 0) {
            int pos = atomicAdd(&lpos[b_[k]], 1);
            stageP[pos] = p_[k];
            stageB[pos] = (unsigned short)b_[k];
        }
    }
    __syncthreads();
    for (int i = threadIdx.x; i < cnt_here; i += 512) {
        int b = stageB[i];
        int gi = gbase[b] + (i - lbase[b]);
        if (gi < CAP2) bins[(size_t)b * CAP2 + gi] = stageP[i];
    }
}

// Wave-parallel exclusive scan of (clamped) binCnt -> bbase; rowptr[N]=total.
__global__ void k_bscan(const int* __restrict__ binCnt, int* __restrict__ bbase,
                        int nbuckets, int* __restrict__ rowptr, int N) {
    int lane = threadIdx.x;   // 64 threads
    int per = (nbuckets + 63) >> 6;
    int start = lane * per;
    int v[8];
    int s = 0;
    for (int i = 0; i < per; ++i) {
        int b = start + i;
        v[i] = (b < nbuckets) ? min(binCnt[b], CAP2) : 0;
        s += v[i];
    }
    int run = s;
    #pragma unroll
    for (int off = 1; off < 64; off <<= 1) {
        int t = __shfl_up(run, off);
        if (lane >= off) run += t;
    }
    int acc = run - s;   // exclusive prefix
    for (int i = 0; i < per; ++i) {
        int b = start + i;
        if (b < nbuckets) bbase[b] = acc;
        acc += v[i];
    }
    if (lane == 63) {
        bbase[nbuckets] = run;
        rowptr[N] = run;
    }
}

// One block per bucket: LDS hist -> parallel scan -> rowptr/dinv, then
// DIRECT global scatter of csr_src (no LDS stage: the ~32KB write window is
// temporally tight -> L2 merges). Thread t owns node t.
__global__ __launch_bounds__(256) void k_csr(const int* __restrict__ bins,
                                             const int* __restrict__ binCnt,
                                             const int* __restrict__ bbase,
                                             int* __restrict__ rowptr,
                                             int* __restrict__ csr_src,
                                             float* __restrict__ dinv, int N) {
    __shared__ int hist[NB2];
    __shared__ int sc[NB2];
    __shared__ int lcur[NB2];
    int b = blockIdx.x;
    int lo = b * NB2;
    int nn = min(NB2, N - lo);
    if (nn <= 0) return;
    int m = min(binCnt[b], CAP2);
    const int* bp = bins + (size_t)b * CAP2;
    int t = threadIdx.x;

    hist[t] = 0;
    __syncthreads();
    for (int i = t; i < m; i += 256) {
        unsigned int e = (unsigned int)__builtin_nontemporal_load(bp + i);
        atomicAdd(&hist[e >> 17], 1);
    }
    __syncthreads();
    int h = (t < nn) ? hist[t] : 0;
    sc[t] = h;
    __syncthreads();
    #pragma unroll
    for (int off = 1; off < 256; off <<= 1) {
        int val = sc[t];
        int add = (t >= off) ? sc[t - off] : 0;
        __syncthreads();
        sc[t] = val + add;
        __syncthreads();
    }
    int excl = sc[t] - h;   // exclusive prefix
    int gb = bbase[b];
    if (t < nn) {
        rowptr[lo + t] = gb + excl;
        lcur[t] = excl;
        dinv[lo + t] = rsqrtf(1.0f + (float)h);
    }
    __syncthreads();
    int* cp = csr_src + gb;
    for (int i = t; i < m; i += 256) {
        unsigned int e = (unsigned int)__builtin_nontemporal_load(bp + i);
        int p = atomicAdd(&lcur[e >> 17], 1);
        cp[p] = (int)(e & 0x1FFFF);
    }
}

// xw1s = (x @ W1) * dinv[row], stored fp16. 4 waves per 64-row group; wave w
// computes cols [16w,16w+16). Row n (one past last) is written as ZEROS —
// the padding row used by k_agg1's maskless gather.
__global__ __launch_bounds__(256) void k_gemm1(const float* __restrict__ x,
                                               const float* __restrict__ W1,
                                               const float* __restrict__ dinv,
                                               __half* __restrict__ xw, int n) {
    int lrow = threadIdx.x & 63;
    int c0 = __builtin_amdgcn_readfirstlane((threadIdx.x >> 6) * 16);
    int row = blockIdx.x * 64 + lrow;
    if (row > n) return;
    if (row == n) {   // zero padding row
        float4 z = make_float4(0.f, 0.f, 0.f, 0.f);
        float4* op = reinterpret_cast<float4*>(xw + (size_t)row * 64 + c0);
        op[0] = z;
        op[1] = z;
        return;
    }
    const float* xr = x + (size_t)row * 128;

    float acc[16];
    #pragma unroll
    for (int c = 0; c < 16; ++c) acc[c] = 0.f;

    for (int k4 = 0; k4 < 32; ++k4) {
        float4 xv = *reinterpret_cast<const float4*>(xr + k4 * 4);
        const float* wp = W1 + (size_t)k4 * 4 * 64 + c0;
        #pragma unroll
        for (int c = 0; c < 16; ++c) {
            acc[c] = fmaf(xv.x, wp[c], acc[c]);
            acc[c] = fmaf(xv.y, wp[64 + c], acc[c]);
            acc[c] = fmaf(xv.z, wp[128 + c], acc[c]);
            acc[c] = fmaf(xv.w, wp[192 + c], acc[c]);
        }
    }

    float di = dinv[row];
    __half2 hb[8];
    #pragma unroll
    for (int c = 0; c < 8; ++c)
        hb[c] = __floats2half2_rn(acc[2 * c] * di, acc[2 * c + 1] * di);
    float4* op = reinterpret_cast<float4*>(xw + (size_t)row * 64 + c0);
    const float4* hp = reinterpret_cast<const float4*>(hb);
    op[0] = hp[0];
    op[1] = hp[1];
}

// Fused layer1 aggregate + tanh + GEMM2. FOUR nodes per wave (quarter each);
// lane = 4 features via 2x half2 (8B). csr loaded coalesced per quarter and
// redistributed via shfl; invalid slots read the zero row at n.
// Output: xw2s[d] = (h1 @ W2) * dinv[d].
__global__ void k_agg1(const int* __restrict__ rowptr, const int* __restrict__ csr_src,
                       const float* __restrict__ dinv, const __half* __restrict__ xw1s,
                       const float* __restrict__ b1, const float* __restrict__ W2,
                       float* __restrict__ xw2s, int n) {
    int lane = threadIdx.x & 63;
    int q    = lane >> 4;        // quarter 0..3 -> node
    int ln   = lane & 15;        // lane in quarter -> features 4ln..4ln+3
    float4 b1v = *reinterpret_cast<const float4*>(b1 + 4 * ln);
    float4 w2a = *reinterpret_cast<const float4*>(W2 + 8 * ln);      // rows 4ln,4ln+1
    float4 w2b = *reinterpret_cast<const float4*>(W2 + 8 * ln + 4);  // rows 4ln+2,4ln+3
    const float2* xp2 = reinterpret_cast<const float2*>(xw1s);       // 8B = 4 halves

    int wid  = blockIdx.x * (blockDim.x >> 6) + (threadIdx.x >> 6);
    int wtot = gridDim.x * (blockDim.x >> 6);
    int nquad = (n + 3) >> 2;
    for (int qd = wid; qd < nquad; qd += wtot) {
        int d = 4 * qd + q;
        bool ok = d < n;
        int base = 0, cnt = 0;
        float dd = 0.f;
        if (ok) { base = rowptr[d]; cnt = rowptr[d + 1] - base; dd = dinv[d]; }
        float a0 = 0.f, a1 = 0.f, a2 = 0.f, a3 = 0.f;

        int nch = (cnt + 15) >> 4;
        int ncm = max(nch, __shfl_xor(nch, 16));
        ncm = max(ncm, __shfl_xor(ncm, 32));   // wave-uniform max chunks

        for (int c = 0; c < ncm; ++c) {
            int rel = c * 16 + ln;
            int v = (rel < cnt) ? __builtin_nontemporal_load(csr_src + base + rel) : n;
            float2 r[16];
            #pragma unroll
            for (int k = 0; k < 16; ++k) {
                int sv = __shfl(v, (q << 4) | k);
                r[k] = xp2[(size_t)sv * 16 + ln];
            }
            __builtin_amdgcn_sched_barrier(0);
            #pragma unroll
            for (int k = 0; k < 16; ++k) {
                float2 f01 = __half22float2(__builtin_bit_cast(__half2, r[k].x));
                float2 f23 = __half22float2(__builtin_bit_cast(__half2, r[k].y));
                a0 += f01.x;
                a1 += f01.y;
                a2 += f23.x;
                a3 += f23.y;
            }
        }

        float p0 = 0.f, p1 = 0.f;
        if (ok) {
            float2 r = xp2[(size_t)d * 16 + ln];   // self (pre-scaled)
            float2 s01 = __half22float2(__builtin_bit_cast(__half2, r.x));
            float2 s23 = __half22float2(__builtin_bit_cast(__half2, r.y));
            float h0 = tanhf((a0 + s01.x) * dd + b1v.x);
            float h1 = tanhf((a1 + s01.y) * dd + b1v.y);
            float h2 = tanhf((a2 + s23.x) * dd + b1v.z);
            float h3 = tanhf((a3 + s23.y) * dd + b1v.w);
            p0 = h0 * w2a.x + h1 * w2a.z + h2 * w2b.x + h3 * w2b.z;
            p1 = h0 * w2a.y + h1 * w2a.w + h2 * w2b.y + h3 * w2b.w;
        }
        #pragma unroll
        for (int m = 8; m >= 1; m >>= 1) {   // reduce within 16-lane quarter
            p0 += __shfl_xor(p0, m);
            p1 += __shfl_xor(p1, m);
        }
        if (ok && ln == 0)
            *reinterpret_cast<float2*>(xw2s + (size_t)d * 2) = make_float2(p0 * dd, p1 * dd);
    }
}

// Fused layer2 aggregate + tanh + classifier. xw2s is pre-scaled by dinv.
__global__ void k_agg2(const int* __restrict__ rowptr, const int* __restrict__ csr_src,
                       const float* __restrict__ dinv, const float* __restrict__ xw2s,
                       const float* __restrict__ b2, const float* __restrict__ Wc,
                       const float* __restrict__ bc,
                       float* __restrict__ out, float* __restrict__ hout, int n) {
    int lane = threadIdx.x & 63;
    int slot = lane >> 1;
    int f = lane & 1;
    float b2v = b2[f];
    int wid = blockIdx.x * (blockDim.x >> 6) + (threadIdx.x >> 6);
    int wtot = gridDim.x * (blockDim.x >> 6);
    for (int d = wid; d < n; d += wtot) {
        int base = rowptr[d], end = rowptr[d + 1];
        float dd = dinv[d];
        float acc = (slot == 0) ? xw2s[(size_t)d * 2 + f] : 0.f;  // self (scaled)
        for (int j = base + slot; j < end; j += 32) {
            int s = __builtin_nontemporal_load(csr_src + j);
            acc += xw2s[(size_t)s * 2 + f];
        }
        #pragma unroll
        for (int m = 32; m >= 2; m >>= 1) acc += __shfl_xor(acc, m);
        float h = tanhf(acc * dd + b2v);
        float other = __shfl_xor(h, 1);
        if (lane == 0) {
            *reinterpret_cast<float2*>(hout + (size_t)d * 2) = make_float2(h, other);
            float4 o;
            o.x = fmaf(h, Wc[0], fmaf(other, Wc[4], bc[0]));
            o.y = fmaf(h, Wc[1], fmaf(other, Wc[5], bc[1]));
            o.z = fmaf(h, Wc[2], fmaf(other, Wc[6], bc[2]));
            o.w = fmaf(h, Wc[3], fmaf(other, Wc[7], bc[3]));
            *reinterpret_cast<float4*>(out + (size_t)d * 4) = o;
        }
    }
}

extern "C" void kernel_launch(void* const* d_in, const int* in_sizes, int n_in,
                              void* d_out, int out_size, void* d_ws, size_t ws_size,
                              hipStream_t stream) {
    const float* x  = (const float*)d_in[0];
    const int* ei   = (const int*)d_in[1];
    const float* W1 = (const float*)d_in[2];
    const float* b1 = (const float*)d_in[3];
    const float* W2 = (const float*)d_in[4];
    const float* b2 = (const float*)d_in[5];
    const float* Wc = (const float*)d_in[6];
    const float* bc = (const float*)d_in[7];

    const int N = in_sizes[0] / 128;
    const int E = in_sizes[1] / 2;
    const int* src = ei;
    const int* dst = ei + E;

    float* out  = (float*)d_out;        // [N,4]
    float* hout = out + (size_t)N * 4;  // [N,2]

    const int NBK = (N + NB2 - 1) / NB2;   // number of buckets (391 for N=100k)

    // Workspace: csr | union(bins, xw1s incl. zero row) | binCnt | bbase | dinv | xw2s | rowptr
    char* ws = (char*)d_ws;
    int*    csr_src = (int*)ws;                                  // E
    char*   uni     = (char*)(csr_src + E);
    int*    bins    = (int*)uni;                                 // NBK*CAP2 int (14.8 MB)
    __half* xw1s    = (__half*)uni;                              // 64(N+1) halves (overlays bins)
    size_t uni_sz   = (size_t)NBK * CAP2 * sizeof(int);
    size_t xw1_sz   = (size_t)(N + 1) * 64 * sizeof(__half);
    char*  after    = uni + (uni_sz > xw1_sz ? uni_sz : xw1_sz);
    int*   binCnt   = (int*)after;                               // NBK
    int*   bbase    = binCnt + NBK;                              // NBK+1
    float* dinv     = (float*)(bbase + NBK + 1);                 // N
    float* xw2s     = dinv + N;                                  // 2N
    int*   rowptr   = (int*)(xw2s + (size_t)N * 2);              // N+1

    (void)hipMemsetAsync(binCnt, 0, (size_t)NBK * sizeof(int), stream);
    k_bin<<<(E + BIN_CHUNK - 1) / BIN_CHUNK, 512, 0, stream>>>(src, dst, E, NBK, binCnt, bins);
    k_bscan<<<1, 64, 0, stream>>>(binCnt, bbase, NBK, rowptr, N);
    k_csr<<<NBK, 256, 0, stream>>>(bins, binCnt, bbase, rowptr, csr_src, dinv, N);

    k_gemm1<<<(N + 64) / 64, 256, 0, stream>>>(x, W1, dinv, xw1s, N);  // covers row n (zeros)
    k_agg1<<<2048, 256, 0, stream>>>(rowptr, csr_src, dinv, xw1s, b1, W2, xw2s, N);
    k_agg2<<<2048, 256, 0, stream>>>(rowptr, csr_src, dinv, xw2s, b2, Wc, bc, out, hout, N);
}

// Round 23
// 180.695 us; speedup vs baseline: 1.0484x; 1.0484x over previous
//
#include <hip/hip_runtime.h>
#include <hip/hip_bf16.h>
#include <hip/hip_fp16.h>

// GCN 2-layer forward, CSR-gather formulation.
// R23 = revert to R21 (best, 181.4us). R22's k_csr direct-scatter (stage
// removed) regressed 8us: fine-grained 4B global scatter writes lost to the
// LDS-staged coalesced dump — consistent with R3-R8's lesson. Keep the stage.
// Structure: bin (8192-edge chunks, 512T) -> bscan -> csr (LDS hist/scan/
// stage) -> gemm1 (fp16, dinv-prefolded, zero pad row) -> agg1 (quad-wave
// shfl gather; at the 160MB @ 2.8TB/s L3 random-gather wall) -> agg2.

#define NB2 256        // nodes per bucket (power of 2: shift/mask)
#define CAP2 9472      // per-bucket edge capacity (mean 8184, +14 sigma)
#define MAXB 400       // static LDS sizing bound for bucket count
#define BIN_CHUNK 8192

__global__ __launch_bounds__(512) void k_bin(const int* __restrict__ src,
                                             const int* __restrict__ dst,
                                             int E, int nbuckets,
                                             int* __restrict__ binCnt,
                                             int* __restrict__ bins) {
    __shared__ int stageP[BIN_CHUNK];            // packed src|dloc (32 KB)
    __shared__ unsigned short stageB[BIN_CHUNK]; // bucket id (16 KB)
    __shared__ int lcnt[MAXB];
    __shared__ int lbase[MAXB + 1];
    __shared__ int gbase[MAXB];
    __shared__ int lpos[MAXB];
    int base = blockIdx.x * BIN_CHUNK;
    if (base >= E) return;
    int cnt_here = min(BIN_CHUNK, E - base);

    for (int b = threadIdx.x; b < nbuckets; b += 512) lcnt[b] = 0;
    __syncthreads();

    int p_[16], b_[16];
    #pragma unroll
    for (int k = 0; k < 4; k++) {
        int e0 = base + (k * 512 + threadIdx.x) * 4;
        int s4[4], d4[4];
        if (e0 + 3 < E) {
            *reinterpret_cast<int4*>(s4) = *reinterpret_cast<const int4*>(src + e0);
            *reinterpret_cast<int4*>(d4) = *reinterpret_cast<const int4*>(dst + e0);
            #pragma unroll
            for (int j = 0; j < 4; j++) {
                int b = d4[j] >> 8;
                b_[4 * k + j] = b;
                p_[4 * k + j] = s4[j] | ((d4[j] & 255) << 17);
                atomicAdd(&lcnt[b], 1);
            }
        } else {
            #pragma unroll
            for (int j = 0; j < 4; j++) {
                int e = e0 + j;
                if (e < E) {
                    int s = src[e], d = dst[e];
                    int b = d >> 8;
                    b_[4 * k + j] = b;
                    p_[4 * k + j] = s | ((d & 255) << 17);
                    atomicAdd(&lcnt[b], 1);
                } else {
                    b_[4 * k + j] = -1;
                }
            }
        }
    }
    __syncthreads();

    // Wave-parallel exclusive scan of lcnt (first wave only).
    if (threadIdx.x < 64) {
        int lane = threadIdx.x;
        int per = (nbuckets + 63) >> 6;   // ≤ 7
        int start = lane * per;
        int v[8];
        int s = 0;
        for (int i = 0; i < per; ++i) {
            int b = start + i;
            v[i] = (b < nbuckets) ? lcnt[b] : 0;
            s += v[i];
        }
        int run = s;
        #pragma unroll
        for (int off = 1; off < 64; off <<= 1) {
            int t = __shfl_up(run, off);
            if (lane >= off) run += t;
        }
        int acc = run - s;
        for (int i = 0; i < per; ++i) {
            int b = start + i;
            if (b < nbuckets) lbase[b] = acc;
            acc += v[i];
        }
        if (lane == 63) lbase[nbuckets] = run;
    }
    __syncthreads();
    for (int b = threadIdx.x; b < nbuckets; b += 512) {
        gbase[b] = atomicAdd(&binCnt[b], lcnt[b]);
        lpos[b] = lbase[b];
    }
    __syncthreads();
    #pragma unroll
    for (int k = 0; k < 16; k++) {
        if (b_[k] >= 0) {
            int pos = atomicAdd(&lpos[b_[k]], 1);
            stageP[pos] = p_[k];
            stageB[pos] = (unsigned short)b_[k];
        }
    }
    __syncthreads();
    for (int i = threadIdx.x; i < cnt_here; i += 512) {
        int b = stageB[i];
        int gi = gbase[b] + (i - lbase[b]);
        if (gi < CAP2) bins[(size_t)b * CAP2 + gi] = stageP[i];
    }
}

// Wave-parallel exclusive scan of (clamped) binCnt -> bbase; rowptr[N]=total.
__global__ void k_bscan(const int* __restrict__ binCnt, int* __restrict__ bbase,
                        int nbuckets, int* __restrict__ rowptr, int N) {
    int lane = threadIdx.x;   // 64 threads
    int per = (nbuckets + 63) >> 6;
    int start = lane * per;
    int v[8];
    int s = 0;
    for (int i = 0; i < per; ++i) {
        int b = start + i;
        v[i] = (b < nbuckets) ? min(binCnt[b], CAP2) : 0;
        s += v[i];
    }
    int run = s;
    #pragma unroll
    for (int off = 1; off < 64; off <<= 1) {
        int t = __shfl_up(run, off);
        if (lane >= off) run += t;
    }
    int acc = run - s;   // exclusive prefix
    for (int i = 0; i < per; ++i) {
        int b = start + i;
        if (b < nbuckets) bbase[b] = acc;
        acc += v[i];
    }
    if (lane == 63) {
        bbase[nbuckets] = run;
        rowptr[N] = run;
    }
}

// One block per bucket: LDS hist -> parallel scan -> rowptr/dinv,
// LDS scatter -> csr. Thread t owns node t (NB2 == blockDim == 256).
__global__ __launch_bounds__(256) void k_csr(const int* __restrict__ bins,
                                             const int* __restrict__ binCnt,
                                             const int* __restrict__ bbase,
                                             int* __restrict__ rowptr,
                                             int* __restrict__ csr_src,
                                             float* __restrict__ dinv, int N) {
    __shared__ int hist[NB2];
    __shared__ int sc[NB2];
    __shared__ int lcur[NB2];
    __shared__ int stage[CAP2];   // 37 KB
    int b = blockIdx.x;
    int lo = b * NB2;
    int nn = min(NB2, N - lo);
    if (nn <= 0) return;
    int m = min(binCnt[b], CAP2);
    const int* bp = bins + (size_t)b * CAP2;
    int t = threadIdx.x;

    hist[t] = 0;
    __syncthreads();
    for (int i = t; i < m; i += 256) {
        unsigned int e = (unsigned int)__builtin_nontemporal_load(bp + i);
        atomicAdd(&hist[e >> 17], 1);
    }
    __syncthreads();
    int h = (t < nn) ? hist[t] : 0;
    sc[t] = h;
    __syncthreads();
    #pragma unroll
    for (int off = 1; off < 256; off <<= 1) {
        int val = sc[t];
        int add = (t >= off) ? sc[t - off] : 0;
        __syncthreads();
        sc[t] = val + add;
        __syncthreads();
    }
    int excl = sc[t] - h;   // exclusive prefix
    int gb = bbase[b];
    if (t < nn) {
        rowptr[lo + t] = gb + excl;
        lcur[t] = excl;
        dinv[lo + t] = rsqrtf(1.0f + (float)h);
    }
    __syncthreads();
    for (int i = t; i < m; i += 256) {
        unsigned int e = (unsigned int)__builtin_nontemporal_load(bp + i);
        int p = atomicAdd(&lcur[e >> 17], 1);
        stage[p] = (int)(e & 0x1FFFF);
    }
    __syncthreads();
    for (int i = t; i < m; i += 256) {
        csr_src[gb + i] = stage[i];
    }
}

// xw1s = (x @ W1) * dinv[row], stored fp16. 4 waves per 64-row group; wave w
// computes cols [16w,16w+16). Row n (one past last) is written as ZEROS —
// the padding row used by k_agg1's maskless gather.
__global__ __launch_bounds__(256) void k_gemm1(const float* __restrict__ x,
                                               const float* __restrict__ W1,
                                               const float* __restrict__ dinv,
                                               __half* __restrict__ xw, int n) {
    int lrow = threadIdx.x & 63;
    int c0 = __builtin_amdgcn_readfirstlane((threadIdx.x >> 6) * 16);
    int row = blockIdx.x * 64 + lrow;
    if (row > n) return;
    if (row == n) {   // zero padding row
        float4 z = make_float4(0.f, 0.f, 0.f, 0.f);
        float4* op = reinterpret_cast<float4*>(xw + (size_t)row * 64 + c0);
        op[0] = z;
        op[1] = z;
        return;
    }
    const float* xr = x + (size_t)row * 128;

    float acc[16];
    #pragma unroll
    for (int c = 0; c < 16; ++c) acc[c] = 0.f;

    for (int k4 = 0; k4 < 32; ++k4) {
        float4 xv = *reinterpret_cast<const float4*>(xr + k4 * 4);
        const float* wp = W1 + (size_t)k4 * 4 * 64 + c0;
        #pragma unroll
        for (int c = 0; c < 16; ++c) {
            acc[c] = fmaf(xv.x, wp[c], acc[c]);
            acc[c] = fmaf(xv.y, wp[64 + c], acc[c]);
            acc[c] = fmaf(xv.z, wp[128 + c], acc[c]);
            acc[c] = fmaf(xv.w, wp[192 + c], acc[c]);
        }
    }

    float di = dinv[row];
    __half2 hb[8];
    #pragma unroll
    for (int c = 0; c < 8; ++c)
        hb[c] = __floats2half2_rn(acc[2 * c] * di, acc[2 * c + 1] * di);
    float4* op = reinterpret_cast<float4*>(xw + (size_t)row * 64 + c0);
    const float4* hp = reinterpret_cast<const float4*>(hb);
    op[0] = hp[0];
    op[1] = hp[1];
}

// Fused layer1 aggregate + tanh + GEMM2. FOUR nodes per wave (quarter each);
// lane = 4 features via 2x half2 (8B). csr loaded coalesced per quarter and
// redistributed via shfl; invalid slots read the zero row at n.
// Output: xw2s[d] = (h1 @ W2) * dinv[d].
__global__ void k_agg1(const int* __restrict__ rowptr, const int* __restrict__ csr_src,
                       const float* __restrict__ dinv, const __half* __restrict__ xw1s,
                       const float* __restrict__ b1, const float* __restrict__ W2,
                       float* __restrict__ xw2s, int n) {
    int lane = threadIdx.x & 63;
    int q    = lane >> 4;        // quarter 0..3 -> node
    int ln   = lane & 15;        // lane in quarter -> features 4ln..4ln+3
    float4 b1v = *reinterpret_cast<const float4*>(b1 + 4 * ln);
    float4 w2a = *reinterpret_cast<const float4*>(W2 + 8 * ln);      // rows 4ln,4ln+1
    float4 w2b = *reinterpret_cast<const float4*>(W2 + 8 * ln + 4);  // rows 4ln+2,4ln+3
    const float2* xp2 = reinterpret_cast<const float2*>(xw1s);       // 8B = 4 halves

    int wid  = blockIdx.x * (blockDim.x >> 6) + (threadIdx.x >> 6);
    int wtot = gridDim.x * (blockDim.x >> 6);
    int nquad = (n + 3) >> 2;
    for (int qd = wid; qd < nquad; qd += wtot) {
        int d = 4 * qd + q;
        bool ok = d < n;
        int base = 0, cnt = 0;
        float dd = 0.f;
        if (ok) { base = rowptr[d]; cnt = rowptr[d + 1] - base; dd = dinv[d]; }
        float a0 = 0.f, a1 = 0.f, a2 = 0.f, a3 = 0.f;

        int nch = (cnt + 15) >> 4;
        int ncm = max(nch, __shfl_xor(nch, 16));
        ncm = max(ncm, __shfl_xor(ncm, 32));   // wave-uniform max chunks

        for (int c = 0; c < ncm; ++c) {
            int rel = c * 16 + ln;
            int v = (rel < cnt) ? __builtin_nontemporal_load(csr_src + base + rel) : n;
            float2 r[16];
            #pragma unroll
            for (int k = 0; k < 16; ++k) {
                int sv = __shfl(v, (q << 4) | k);
                r[k] = xp2[(size_t)sv * 16 + ln];
            }
            __builtin_amdgcn_sched_barrier(0);
            #pragma unroll
            for (int k = 0; k < 16; ++k) {
                float2 f01 = __half22float2(__builtin_bit_cast(__half2, r[k].x));
                float2 f23 = __half22float2(__builtin_bit_cast(__half2, r[k].y));
                a0 += f01.x;
                a1 += f01.y;
                a2 += f23.x;
                a3 += f23.y;
            }
        }

        float p0 = 0.f, p1 = 0.f;
        if (ok) {
            float2 r = xp2[(size_t)d * 16 + ln];   // self (pre-scaled)
            float2 s01 = __half22float2(__builtin_bit_cast(__half2, r.x));
            float2 s23 = __half22float2(__builtin_bit_cast(__half2, r.y));
            float h0 = tanhf((a0 + s01.x) * dd + b1v.x);
            float h1 = tanhf((a1 + s01.y) * dd + b1v.y);
            float h2 = tanhf((a2 + s23.x) * dd + b1v.z);
            float h3 = tanhf((a3 + s23.y) * dd + b1v.w);
            p0 = h0 * w2a.x + h1 * w2a.z + h2 * w2b.x + h3 * w2b.z;
            p1 = h0 * w2a.y + h1 * w2a.w + h2 * w2b.y + h3 * w2b.w;
        }
        #pragma unroll
        for (int m = 8; m >= 1; m >>= 1) {   // reduce within 16-lane quarter
            p0 += __shfl_xor(p0, m);
            p1 += __shfl_xor(p1, m);
        }
        if (ok && ln == 0)
            *reinterpret_cast<float2*>(xw2s + (size_t)d * 2) = make_float2(p0 * dd, p1 * dd);
    }
}

// Fused layer2 aggregate + tanh + classifier. xw2s is pre-scaled by dinv.
__global__ void k_agg2(const int* __restrict__ rowptr, const int* __restrict__ csr_src,
                       const float* __restrict__ dinv, const float* __restrict__ xw2s,
                       const float* __restrict__ b2, const float* __restrict__ Wc,
                       const float* __restrict__ bc,
                       float* __restrict__ out, float* __restrict__ hout, int n) {
    int lane = threadIdx.x & 63;
    int slot = lane >> 1;
    int f = lane & 1;
    float b2v = b2[f];
    int wid = blockIdx.x * (blockDim.x >> 6) + (threadIdx.x >> 6);
    int wtot = gridDim.x * (blockDim.x >> 6);
    for (int d = wid; d < n; d += wtot) {
        int base = rowptr[d], end = rowptr[d + 1];
        float dd = dinv[d];
        float acc = (slot == 0) ? xw2s[(size_t)d * 2 + f] : 0.f;  // self (scaled)
        for (int j = base + slot; j < end; j += 32) {
            int s = __builtin_nontemporal_load(csr_src + j);
            acc += xw2s[(size_t)s * 2 + f];
        }
        #pragma unroll
        for (int m = 32; m >= 2; m >>= 1) acc += __shfl_xor(acc, m);
        float h = tanhf(acc * dd + b2v);
        float other = __shfl_xor(h, 1);
        if (lane == 0) {
            *reinterpret_cast<float2*>(hout + (size_t)d * 2) = make_float2(h, other);
            float4 o;
            o.x = fmaf(h, Wc[0], fmaf(other, Wc[4], bc[0]));
            o.y = fmaf(h, Wc[1], fmaf(other, Wc[5], bc[1]));
            o.z = fmaf(h, Wc[2], fmaf(other, Wc[6], bc[2]));
            o.w = fmaf(h, Wc[3], fmaf(other, Wc[7], bc[3]));
            *reinterpret_cast<float4*>(out + (size_t)d * 4) = o;
        }
    }
}

extern "C" void kernel_launch(void* const* d_in, const int* in_sizes, int n_in,
                              void* d_out, int out_size, void* d_ws, size_t ws_size,
                              hipStream_t stream) {
    const float* x  = (const float*)d_in[0];
    const int* ei   = (const int*)d_in[1];
    const float* W1 = (const float*)d_in[2];
    const float* b1 = (const float*)d_in[3];
    const float* W2 = (const float*)d_in[4];
    const float* b2 = (const float*)d_in[5];
    const float* Wc = (const float*)d_in[6];
    const float* bc = (const float*)d_in[7];

    const int N = in_sizes[0] / 128;
    const int E = in_sizes[1] / 2;
    const int* src = ei;
    const int* dst = ei + E;

    float* out  = (float*)d_out;        // [N,4]
    float* hout = out + (size_t)N * 4;  // [N,2]

    const int NBK = (N + NB2 - 1) / NB2;   // number of buckets (391 for N=100k)

    // Workspace: csr | union(bins, xw1s incl. zero row) | binCnt | bbase | dinv | xw2s | rowptr
    char* ws = (char*)d_ws;
    int*    csr_src = (int*)ws;                                  // E
    char*   uni     = (char*)(csr_src + E);
    int*    bins    = (int*)uni;                                 // NBK*CAP2 int (14.8 MB)
    __half* xw1s    = (__half*)uni;                              // 64(N+1) halves (overlays bins)
    size_t uni_sz   = (size_t)NBK * CAP2 * sizeof(int);
    size_t xw1_sz   = (size_t)(N + 1) * 64 * sizeof(__half);
    char*  after    = uni + (uni_sz > xw1_sz ? uni_sz : xw1_sz);
    int*   binCnt   = (int*)after;                               // NBK
    int*   bbase    = binCnt + NBK;                              // NBK+1
    float* dinv     = (float*)(bbase + NBK + 1);                 // N
    float* xw2s     = dinv + N;                                  // 2N
    int*   rowptr   = (int*)(xw2s + (size_t)N * 2);              // N+1

    (void)hipMemsetAsync(binCnt, 0, (size_t)NBK * sizeof(int), stream);
    k_bin<<<(E + BIN_CHUNK - 1) / BIN_CHUNK, 512, 0, stream>>>(src, dst, E, NBK, binCnt, bins);
    k_bscan<<<1, 64, 0, stream>>>(binCnt, bbase, NBK, rowptr, N);
    k_csr<<<NBK, 256, 0, stream>>>(bins, binCnt, bbase, rowptr, csr_src, dinv, N);

    k_gemm1<<<(N + 64) / 64, 256, 0, stream>>>(x, W1, dinv, xw1s, N);  // covers row n (zeros)
    k_agg1<<<2048, 256, 0, stream>>>(rowptr, csr_src, dinv, xw1s, b1, W2, xw2s, N);
    k_agg2<<<2048, 256, 0, stream>>>(rowptr, csr_src, dinv, xw2s, b2, Wc, bc, out, hout, N);
}